// Round 3
// baseline (4366.397 us; speedup 1.0000x reference)
//
#include <hip/hip_runtime.h>

// VoiceModel: 2 branches x { scalar-LSTM(1->1,L2) over T=512 per (b,class),
// then LSTM(1->256,L2) over 128 class-steps }, concat -> MLP(512->200->128).
// Round 3: hidden-dim N-split across blocks; weight slices register-resident
// (128 VGPR/lane); per-step h-slice exchange through L2 with device-scope
// release/acquire flags. Fragment math identical to rounds 1-2 (verified).

typedef _Float16 f16;
typedef __attribute__((ext_vector_type(4))) _Float16 f16x4;
typedef __attribute__((ext_vector_type(8))) _Float16 f16x8;
typedef __attribute__((ext_vector_type(4))) float f32x4;

#define NBATCH 256
#define NTIME  512
#define NCLS   128
#define NHID   256

__device__ __forceinline__ float sigf(float x) {
    return __builtin_amdgcn_rcpf(1.0f + __expf(-x));
}
__device__ __forceinline__ float tanh_f(float x) {
    return fmaf(2.0f, __builtin_amdgcn_rcpf(1.0f + __expf(-2.0f * x)), -1.0f);
}
__device__ __forceinline__ f16x4 LO(f16x8 v) { f16x4 r; r[0]=v[0]; r[1]=v[1]; r[2]=v[2]; r[3]=v[3]; return r; }
__device__ __forceinline__ f16x4 HI(f16x8 v) { f16x4 r; r[0]=v[4]; r[1]=v[5]; r[2]=v[6]; r[3]=v[7]; return r; }

// ---------------- K0: convert + swizzle 6 weight matrices (1024x256) to f16 --
// layout per matrix: elem ((g*16+f)*8+ktp)*512 + (fq*16+fr)*8 + e
//   = W[g*256 + f*16 + fr][(ktp*2+(e>>2))*16 + fq*4 + (e&3)]
struct P6 {
    const float* s0; const float* s1; const float* s2;
    const float* s3; const float* s4; const float* s5;
};

__global__ __launch_bounds__(256) void k_cvt(P6 p, f16* __restrict__ dst) {
    int i = blockIdx.x * 256 + threadIdx.x;      // 6 * 262144 total
    int seg = i >> 18, d = i & 262143;
    const float* s = seg == 0 ? p.s0 : seg == 1 ? p.s1 : seg == 2 ? p.s2
                   : seg == 3 ? p.s3 : seg == 4 ? p.s4 : p.s5;
    const int e  = d & 7;
    const int fr = (d >> 3) & 15;
    const int fq = (d >> 7) & 3;
    const int ktp = (d >> 9) & 7;
    const int f  = (d >> 12) & 15;
    const int g  = (d >> 16) & 3;
    const int row = g * 256 + f * 16 + fr;
    const int col = ktp * 32 + (e >> 2) * 16 + fq * 4 + (e & 3);
    dst[i] = (f16)s[row * 256 + col];
}

// ---------------- zero the exchange flags (every call; graph-replay safe) ----
__global__ void k_zero(int* __restrict__ f) { f[threadIdx.x] = 0; }

// ---------------- K1: scalar 2-layer LSTM per (branch, b, class) -------------
__global__ __launch_bounds__(128) void k_scalar_lstm(
    const int* __restrict__ ln, const int* __restrict__ rn,
    const float* __restrict__ tlW, const float* __restrict__ tlU, const float* __restrict__ tlb,
    const float* __restrict__ trW, const float* __restrict__ trU, const float* __restrict__ trb,
    float* __restrict__ states)
{
    __shared__ int tok[NTIME];
    const int bid = blockIdx.x;
    const int branch = bid >> 8;
    const int b = bid & 255;
    const int* tp = (branch ? rn : ln) + (size_t)b * (4 * NTIME);  // voice 0
    for (int i = threadIdx.x; i < NTIME; i += 128) tok[i] = tp[i];
    __syncthreads();
    const float* W  = branch ? trW : tlW;
    const float* U  = branch ? trU : tlU;
    const float* Bb = branch ? trb : tlb;
    const float u00 = U[0], u01 = U[1], u02 = U[2], u03 = U[3];
    const float f00 = Bb[0], f01 = Bb[1], f02 = Bb[2], f03 = Bb[3];
    const float o00 = f00 + W[0], o01 = f01 + W[1], o02 = f02 + W[2], o03 = f03 + W[3];
    const float w10 = W[4], w11 = W[5], w12 = W[6], w13 = W[7];
    const float u10 = U[4], u11 = U[5], u12 = U[6], u13 = U[7];
    const float b10 = Bb[4], b11 = Bb[5], b12 = Bb[6], b13 = Bb[7];
    const int n = threadIdx.x;
    float h0 = 0.f, c0 = 0.f, h1 = 0.f, c1 = 0.f;
    for (int t = 0; t < NTIME; ++t) {
        const bool x = (tok[t] == n);
        float pi = fmaf(u00, h0, x ? o00 : f00);
        float pf = fmaf(u01, h0, x ? o01 : f01);
        float pg = fmaf(u02, h0, x ? o02 : f02);
        float po = fmaf(u03, h0, x ? o03 : f03);
        float ig = sigf(pi), fg = sigf(pf), gg = tanh_f(pg), og = sigf(po);
        c0 = fmaf(fg, c0, ig * gg);
        h0 = og * tanh_f(c0);
        pi = fmaf(w10, h0, fmaf(u10, h1, b10));
        pf = fmaf(w11, h0, fmaf(u11, h1, b11));
        pg = fmaf(w12, h0, fmaf(u12, h1, b12));
        po = fmaf(w13, h0, fmaf(u13, h1, b13));
        ig = sigf(pi); fg = sigf(pf); gg = tanh_f(pg); og = sigf(po);
        c1 = fmaf(fg, c1, ig * gg);
        h1 = og * tanh_f(c1);
    }
    states[((size_t)(branch * NBATCH + b)) * NCLS + n] = h1;
}

// ---------------- K2: layer-0 recurrence, N-split/4, resident weights ---------
// grid 128 = q(4) * 32 + group(32);  group = branch*16 + tile.  256 thr, 4 waves.
// wave w owns hidden frag fragi = q*4+w (rows g*256+fragi*16+fr, all 4 gates).
// h image (16x256 f16, 8KB) in LDS; per step: own 2KB chunk -> h0img[group][t],
// flag release, spin-acquire 3 peers, pull their chunks.
__global__ __launch_bounds__(256, 2) void k_rec0(
    const float* __restrict__ states,
    const f16* __restrict__ whh0,          // swizzled, [2 branches]
    const float* __restrict__ wih0L, const float* __restrict__ wih0R,
    const float* __restrict__ bL, const float* __restrict__ bR,
    f16* __restrict__ h0img,               // [32 group][128 t][4096]
    int* __restrict__ flags)               // [32 group][4]
{
    __shared__ f16 img[4096];
    __shared__ float lst[16 * NCLS];
    const int bid = blockIdx.x;
    const int q = bid >> 5, group = bid & 31;
    const int branch = group >> 4, tb = group & 15;
    const int tid = threadIdx.x;
    const int w = tid >> 6, l = tid & 63, fr = l & 15, fq = l >> 4;
    const int fragi = q * 4 + w;

    // resident weight slice: 128 VGPRs/lane
    f16x4 wreg[4][16];
    const f16* wbase = whh0 + ((size_t)branch << 18) + (fq * 16 + fr) * 8;
#pragma unroll
    for (int g = 0; g < 4; ++g)
#pragma unroll
        for (int ktp = 0; ktp < 8; ++ktp) {
            f16x8 v = *(const f16x8*)(wbase + (((g * 16 + fragi) * 8 + ktp) << 9));
            wreg[g][2 * ktp]     = LO(v);
            wreg[g][2 * ktp + 1] = HI(v);
        }
    const float* bias = branch ? bR : bL;
    const float* w0   = branch ? wih0R : wih0L;
    float bv[4], w0v[4];
#pragma unroll
    for (int g = 0; g < 4; ++g) {
        const int row = g * 256 + fragi * 16 + fr;
        bv[g] = bias[row];
        w0v[g] = w0[row];
    }
    ((uint4*)img)[tid] = (uint4){0u, 0u, 0u, 0u};
    ((uint4*)img)[tid + 256] = (uint4){0u, 0u, 0u, 0u};
    for (int i = tid; i < 16 * NCLS; i += 256)
        lst[i] = states[((size_t)(branch * NBATCH + tb * 16 + (i >> 7))) * NCLS + (i & 127)];
    float c[4] = {0.f, 0.f, 0.f, 0.f};
    f16* gimg = h0img + (size_t)group * (NCLS * 4096);
    int* flg = flags + group * 4;
    __syncthreads();

    for (int t = 0; t < NCLS; ++t) {
        f16x4 af[16];
#pragma unroll
        for (int kt = 0; kt < 16; ++kt)
            af[kt] = *(const f16x4*)(img + kt * 256 + l * 4);
        f32x4 acc[4];
#pragma unroll
        for (int g = 0; g < 4; ++g) { f32x4 z = {0.f, 0.f, 0.f, 0.f}; acc[g] = z; }
#pragma unroll
        for (int kt = 0; kt < 16; ++kt)
#pragma unroll
            for (int g = 0; g < 4; ++g)
                acc[g] = __builtin_amdgcn_mfma_f32_16x16x16f16(af[kt], wreg[g][kt], acc[g], 0, 0, 0);

        float hn[4];
#pragma unroll
        for (int r = 0; r < 4; ++r) {
            const float st = lst[(fq * 4 + r) * NCLS + t];
            const float pi = fmaf(st, w0v[0], acc[0][r] + bv[0]);
            const float pf = fmaf(st, w0v[1], acc[1][r] + bv[1]);
            const float pg = fmaf(st, w0v[2], acc[2][r] + bv[2]);
            const float po = fmaf(st, w0v[3], acc[3][r] + bv[3]);
            const float ig = sigf(pi), fg = sigf(pf), gg = tanh_f(pg), og = sigf(po);
            c[r] = fmaf(fg, c[r], ig * gg);
            hn[r] = og * tanh_f(c[r]);
        }
        __syncthreads();                       // all af reads of img done
#pragma unroll
        for (int r = 0; r < 4; ++r) {
            const int k = fragi * 16 + fr, m = fq * 4 + r;
            img[(k >> 4) * 256 + (m + 16 * ((k & 15) >> 2)) * 4 + (k & 3)] = (f16)hn[r];
        }
        __syncthreads();                       // own chunk complete in LDS
        f16* gdst = gimg + (size_t)t * 4096;
        ((uint2*)gdst)[q * 256 + tid] = ((const uint2*)img)[q * 256 + tid];
        if (t == NCLS - 1) break;
        __syncthreads();                       // vmcnt(0): chunk stores drained
        __threadfence();
        if (tid == 0)
            __hip_atomic_store(&flg[q], t + 1, __ATOMIC_RELEASE, __HIP_MEMORY_SCOPE_AGENT);
        if (tid < 3) {
            const int p = tid + (tid >= q);
            while (__hip_atomic_load(&flg[p], __ATOMIC_ACQUIRE, __HIP_MEMORY_SCOPE_AGENT) <= t)
                __builtin_amdgcn_s_sleep(2);
        }
        __syncthreads();                       // peers ready; L1 invalidated
        uint2 tmp[3];
#pragma unroll
        for (int j = 0; j < 3; ++j) {
            const int p = j + (j >= q);
            tmp[j] = ((const uint2*)gdst)[p * 256 + tid];
        }
#pragma unroll
        for (int j = 0; j < 3; ++j) {
            const int p = j + (j >= q);
            ((uint2*)img)[p * 256 + tid] = tmp[j];
        }
        __syncthreads();                       // img(t) complete
    }
}

// ---------------- K3: layer-1 recurrence, N-split/8, resident weights ---------
// grid 256 = q(8)*32 + group(32). waves 0,1: recurrent (Whh1 slice resident,
// frag 2q+w); waves 2,3: input path (Wih1 slice resident, reads h0img[group][t]).
// Combine via LDS cmb; h1 slices exchanged through depth-4 ring.
__global__ __launch_bounds__(256, 2) void k_rec1(
    const f16* __restrict__ whh1,          // swizzled
    const f16* __restrict__ wih1,          // swizzled
    const f16* __restrict__ h0img,         // [32][128][4096]
    const float* __restrict__ bL, const float* __restrict__ bR,
    f16* __restrict__ ring,                // [32 group][4 slot][4096]
    int* __restrict__ flags,               // [32 group][8]
    float* __restrict__ h1out)             // [2][256][256] f32
{
    __shared__ f16 img[4096];              // h1 image
    __shared__ float cmb[2][4][16][16];    // input-path pre-activations
    const int bid = blockIdx.x;
    const int q = bid >> 5, group = bid & 31;
    const int branch = group >> 4, tb = group & 15;
    const int tid = threadIdx.x;
    const int w = tid >> 6, l = tid & 63, fr = l & 15, fq = l >> 4;
    const int isB = (w >> 1);              // 0: recurrent waves, 1: input waves
    const int wp = w & 1;                  // hidden sub-frag within block
    const int fragi = q * 2 + wp;

    f16x4 wreg[4][16];
    const f16* mat = (isB ? wih1 : whh1) + ((size_t)branch << 18) + (fq * 16 + fr) * 8;
#pragma unroll
    for (int g = 0; g < 4; ++g)
#pragma unroll
        for (int ktp = 0; ktp < 8; ++ktp) {
            f16x8 v = *(const f16x8*)(mat + (((g * 16 + fragi) * 8 + ktp) << 9));
            wreg[g][2 * ktp]     = LO(v);
            wreg[g][2 * ktp + 1] = HI(v);
        }
    const float* bias = branch ? bR : bL;
    float bv[4];
#pragma unroll
    for (int g = 0; g < 4; ++g) bv[g] = bias[g * 256 + fragi * 16 + fr];

    ((uint4*)img)[tid] = (uint4){0u, 0u, 0u, 0u};
    ((uint4*)img)[tid + 256] = (uint4){0u, 0u, 0u, 0u};
    float c[4] = {0.f, 0.f, 0.f, 0.f};
    const f16* gimg = h0img + (size_t)group * (NCLS * 4096);
    f16* gring = ring + (size_t)group * (4 * 4096);
    int* flg = flags + group * 8;
    __syncthreads();

    for (int t = 0; t < NCLS; ++t) {
        f16x4 af[16];
        if (isB) {
            const f16* src = gimg + (size_t)t * 4096 + l * 4;
#pragma unroll
            for (int kt = 0; kt < 16; ++kt) af[kt] = *(const f16x4*)(src + kt * 256);
        } else {
#pragma unroll
            for (int kt = 0; kt < 16; ++kt) af[kt] = *(const f16x4*)(img + kt * 256 + l * 4);
        }
        f32x4 acc[4];
#pragma unroll
        for (int g = 0; g < 4; ++g) { f32x4 z = {0.f, 0.f, 0.f, 0.f}; acc[g] = z; }
#pragma unroll
        for (int kt = 0; kt < 16; ++kt)
#pragma unroll
            for (int g = 0; g < 4; ++g)
                acc[g] = __builtin_amdgcn_mfma_f32_16x16x16f16(af[kt], wreg[g][kt], acc[g], 0, 0, 0);

        if (isB) {
#pragma unroll
            for (int g = 0; g < 4; ++g)
#pragma unroll
                for (int r = 0; r < 4; ++r)
                    cmb[wp][g][fq * 4 + r][fr] = acc[g][r];
        }
        __syncthreads();                       // cmb ready; img af-reads done
        if (!isB) {
            float hn[4];
#pragma unroll
            for (int r = 0; r < 4; ++r) {
                const int m = fq * 4 + r;
                const float pi = acc[0][r] + cmb[wp][0][m][fr] + bv[0];
                const float pf = acc[1][r] + cmb[wp][1][m][fr] + bv[1];
                const float pg = acc[2][r] + cmb[wp][2][m][fr] + bv[2];
                const float po = acc[3][r] + cmb[wp][3][m][fr] + bv[3];
                const float ig = sigf(pi), fg = sigf(pf), gg = tanh_f(pg), og = sigf(po);
                c[r] = fmaf(fg, c[r], ig * gg);
                hn[r] = og * tanh_f(c[r]);
            }
            if (t == NCLS - 1) {
#pragma unroll
                for (int r = 0; r < 4; ++r)
                    h1out[((size_t)(branch * NBATCH + tb * 16 + fq * 4 + r)) * NHID
                          + fragi * 16 + fr] = hn[r];
            } else {
#pragma unroll
                for (int r = 0; r < 4; ++r) {
                    const int k = fragi * 16 + fr, m = fq * 4 + r;
                    img[(k >> 4) * 256 + (m + 16 * ((k & 15) >> 2)) * 4 + (k & 3)] = (f16)hn[r];
                }
            }
        }
        if (t == NCLS - 1) break;
        __syncthreads();                       // own chunk complete in LDS
        f16* gdst = gring + (size_t)(t & 3) * 4096;
        if (tid < 128)
            ((uint2*)gdst)[q * 128 + tid] = ((const uint2*)img)[q * 128 + tid];
        __syncthreads();                       // vmcnt(0): chunk stores drained
        __threadfence();
        if (tid == 0)
            __hip_atomic_store(&flg[q], t + 1, __ATOMIC_RELEASE, __HIP_MEMORY_SCOPE_AGENT);
        if (tid < 7) {
            const int p = tid + (tid >= q);
            while (__hip_atomic_load(&flg[p], __ATOMIC_ACQUIRE, __HIP_MEMORY_SCOPE_AGENT) <= t)
                __builtin_amdgcn_s_sleep(2);
        }
        __syncthreads();                       // peers ready; L1 invalidated
        if (tid < 128) {
            uint2 tmp[7];
#pragma unroll
            for (int j = 0; j < 7; ++j) {
                const int p = j + (j >= q);
                tmp[j] = ((const uint2*)gdst)[p * 128 + tid];
            }
#pragma unroll
            for (int j = 0; j < 7; ++j) {
                const int p = j + (j >= q);
                ((uint2*)img)[p * 128 + tid] = tmp[j];
            }
        }
        __syncthreads();                       // img(t) complete
    }
}

// ---------------- K4: MLP head (2H -> 200 -> 128), f32 ------------------------
__global__ __launch_bounds__(256) void k_mlp(
    const float* __restrict__ h1all,   // [2][256][256]
    const float* __restrict__ W1, const float* __restrict__ b1,
    const float* __restrict__ W2, const float* __restrict__ b2,
    float* __restrict__ out)
{
    __shared__ float hrow[512];
    __shared__ float hid[200];
    const int b = blockIdx.x, tid = threadIdx.x;
    hrow[tid]       = h1all[(size_t)b * NHID + tid];
    hrow[256 + tid] = h1all[(size_t)(NBATCH + b) * NHID + tid];
    __syncthreads();
    if (tid < 200) {
        float a = b1[tid];
        const float* wr = W1 + (size_t)tid * 512;
        for (int k = 0; k < 512; ++k) a = fmaf(wr[k], hrow[k], a);
        hid[tid] = fmaxf(a, 0.f);
    }
    __syncthreads();
    if (tid < 128) {
        float a = b2[tid];
        const float* wr = W2 + (size_t)tid * 200;
        for (int j = 0; j < 200; ++j) a = fmaf(wr[j], hid[j], a);
        out[(size_t)b * 128 + tid] = a;
    }
}

// ---------------- launch ------------------------------------------------------
extern "C" void kernel_launch(void* const* d_in, const int* in_sizes, int n_in,
                              void* d_out, int out_size, void* d_ws, size_t ws_size,
                              hipStream_t stream)
{
    (void)in_sizes; (void)n_in; (void)out_size; (void)ws_size;
    const int*   ln    = (const int*)d_in[0];
    const int*   rn    = (const int*)d_in[2];
    const float* tlW   = (const float*)d_in[4];
    const float* tlU   = (const float*)d_in[5];
    const float* tlb   = (const float*)d_in[6];
    const float* trW   = (const float*)d_in[7];
    const float* trU   = (const float*)d_in[8];
    const float* trb   = (const float*)d_in[9];
    const float* wih0L = (const float*)d_in[10];
    const float* b0L   = (const float*)d_in[12];
    const float* b1L   = (const float*)d_in[15];
    const float* wih0R = (const float*)d_in[16];
    const float* b0R   = (const float*)d_in[18];
    const float* b1R   = (const float*)d_in[21];
    const float* mW1   = (const float*)d_in[22];
    const float* mb1   = (const float*)d_in[23];
    const float* mW2   = (const float*)d_in[24];
    const float* mb2   = (const float*)d_in[25];

    // workspace layout (bytes)
    char* ws = (char*)d_ws;
    f16*   w16    = (f16*)ws;                        // 3 MB swizzled weights
    float* states = (float*)(ws + 3145728);          // 256 KB
    float* h1out  = (float*)(ws + 3407872);          // 512 KB
    int*   flags  = (int*)(ws + 3932160);            // 128 + 256 ints (4 KB pad)
    f16*   h1ring = (f16*)(ws + 3936256);            // 1 MB
    f16*   h0img  = (f16*)(ws + 4984832);            // 32 MB

    f16* whh0 = w16;
    f16* whh1 = w16 + 2 * 262144;
    f16* wih1 = w16 + 4 * 262144;
    int* flags0 = flags;
    int* flags1 = flags + 128;

    P6 p { (const float*)d_in[11], (const float*)d_in[17],   // nl_Whh0, nr_Whh0
           (const float*)d_in[14], (const float*)d_in[20],   // nl_Whh1, nr_Whh1
           (const float*)d_in[13], (const float*)d_in[19] }; // nl_Wih1, nr_Wih1
    k_zero<<<1, 384, 0, stream>>>(flags);
    k_cvt<<<6144, 256, 0, stream>>>(p, w16);
    k_scalar_lstm<<<512, 128, 0, stream>>>(ln, rn, tlW, tlU, tlb, trW, trU, trb, states);
    k_rec0<<<128, 256, 0, stream>>>(states, whh0, wih0L, wih0R, b0L, b0R, h0img, flags0);
    k_rec1<<<256, 256, 0, stream>>>(whh1, wih1, h0img, b1L, b1R, h1ring, flags1, h1out);
    k_mlp<<<256, 256, 0, stream>>>(h1out, mW1, mb1, mW2, mb2, (float*)d_out);
}